// Round 6
// baseline (272.597 us; speedup 1.0000x reference)
//
#include <hip/hip_runtime.h>

// ---------------------------------------------------------------------------
// TemporalHyperedge: loss[b] = 0.2 * sum_n ||cur[b]@r_proj - W@pre[b]||_2
//                              + sum_n (max_m W[n,m] + 0.001*||W[n,:]||_2)
// W = incidence_m masked to > 0.01. Output = [loss(32) , incidence_m(2048^2)].
//
// R5 change: BK=64/32x32 reverted (stall-per-lgkm-wait worse; measured 106 vs
// 88 us). Back to BK=32 / 16x16x32, PLUS: A operand loaded DIRECTLY from
// global (16B contiguous k per lane) bypassing LDS — removes 0.88 GB of LDS
// traffic (gemm is LDS-pipe-bound: 2.65 GB ≈ 38 us/CU floor) and shrinks the
// pre-barrier GLL drain queue. B stays global_load_lds + LDS (2-way free).
// cur stays f32 (converted in-register in the K-tail — no prep pass).
// ---------------------------------------------------------------------------

typedef __attribute__((ext_vector_type(8))) short bf16x8;
typedef __attribute__((ext_vector_type(8))) unsigned short ushort8;
typedef __attribute__((ext_vector_type(4))) float f32x4;

__device__ __forceinline__ unsigned short f2bf(float f) {
    union { float f; unsigned u; } x; x.f = f;
    unsigned r = x.u + 0x7fffu + ((x.u >> 16) & 1u);   // RNE
    return (unsigned short)(r >> 16);
}

#define GLL16(g, l)                                                         \
    __builtin_amdgcn_global_load_lds(                                       \
        (const __attribute__((address_space(1))) void*)(g),                 \
        (__attribute__((address_space(3))) void*)(l), 16, 0, 0)

// --------------------------------------------------------------------------
// transpose_64x64: src f32 (R,C) tile (r0,c0) -> dst bf16 (C,R).
// --------------------------------------------------------------------------
__device__ __forceinline__ void transpose_64x64(
    const float* __restrict__ src, unsigned short* __restrict__ dst,
    int R, int C, int r0, int c0, unsigned short* __restrict__ tile) {
    const int t = threadIdx.x;
    const int fr = t >> 4, fc = (t & 15) * 4;
#pragma unroll
    for (int it = 0; it < 4; ++it) {
        int m = fr + it * 16;
        float4 v = *(const float4*)(src + (size_t)(r0 + m) * C + c0 + fc);
        tile[(fc + 0) * 68 + m] = f2bf(v.x);
        tile[(fc + 1) * 68 + m] = f2bf(v.y);
        tile[(fc + 2) * 68 + m] = f2bf(v.z);
        tile[(fc + 3) * 68 + m] = f2bf(v.w);
    }
    __syncthreads();
    const int d = t >> 2, m0 = (t & 3) * 16;
    unsigned short v[16];
#pragma unroll
    for (int j = 0; j < 4; ++j)
        *(ushort4*)(v + j * 4) = *(const ushort4*)(tile + d * 68 + m0 + j * 4);
    unsigned short* dp = dst + (size_t)(c0 + d) * R + r0 + m0;
    ushort8 p0, p1;
#pragma unroll
    for (int j = 0; j < 8; ++j) { p0[j] = v[j]; p1[j] = v[8 + j]; }
    *(ushort8*)(dp) = p0;
    *(ushort8*)(dp + 8) = p1;
}

// --------------------------------------------------------------------------
// prep_all — block sections:
//   [0,2048)    : incidence row: copy-out, -masked bf16 W, crow[row]=l1+1e-3*l2
//   [2048,6144) : pre (32,2048,256) -> preT (32,256,2048) bf16 transpose
//   [6144,6160) : r_proj (256,256) -> rprojT bf16 transpose
// --------------------------------------------------------------------------
__global__ __launch_bounds__(256) void prep_all(
    const float* __restrict__ inc, float* __restrict__ out_inc,
    unsigned short* __restrict__ Wneg, float* __restrict__ crow,
    const float* __restrict__ pre, unsigned short* __restrict__ preT,
    const float* __restrict__ r_proj, unsigned short* __restrict__ rprojT) {
    __shared__ unsigned short tile[64 * 68];
    __shared__ float smax[4], ssum[4];
    const int bid = blockIdx.x;
    const int t = threadIdx.x;

    if (bid < 2048) {
        const int row = bid;
        const float4* src = (const float4*)(inc + (size_t)row * 2048);
        float4* dst = (float4*)(out_inc + (size_t)row * 2048);
        ushort4* wp = (ushort4*)(Wneg + (size_t)row * 2048);
        float lmax = 0.f, ss = 0.f;
#pragma unroll
        for (int it = 0; it < 2; ++it) {
            int i = it * 256 + t;
            float4 v = src[i];
            dst[i] = v;
            float w0 = v.x > 0.01f ? v.x : 0.f;
            float w1 = v.y > 0.01f ? v.y : 0.f;
            float w2 = v.z > 0.01f ? v.z : 0.f;
            float w3 = v.w > 0.01f ? v.w : 0.f;
            ushort4 p;
            p.x = f2bf(-w0); p.y = f2bf(-w1); p.z = f2bf(-w2); p.w = f2bf(-w3);
            wp[i] = p;
            lmax = fmaxf(lmax, fmaxf(fmaxf(w0, w1), fmaxf(w2, w3)));
            ss += w0 * w0 + w1 * w1 + w2 * w2 + w3 * w3;
        }
#pragma unroll
        for (int off = 32; off; off >>= 1) {
            lmax = fmaxf(lmax, __shfl_down(lmax, off));
            ss += __shfl_down(ss, off);
        }
        int wv = t >> 6, ln = t & 63;
        if (ln == 0) { smax[wv] = lmax; ssum[wv] = ss; }
        __syncthreads();
        if (t == 0) {
            float m = fmaxf(fmaxf(smax[0], smax[1]), fmaxf(smax[2], smax[3]));
            float s = ssum[0] + ssum[1] + ssum[2] + ssum[3];
            crow[row] = m + 0.001f * sqrtf(s);
        }
    } else if (bid < 6144) {
        const int tt = bid - 2048;
        const int b = tt >> 7;
        const int mt = (tt & 127) >> 2;
        const int dt = tt & 3;
        transpose_64x64(pre + (size_t)b * 524288, preT + (size_t)b * 524288,
                        2048, 256, mt * 64, dt * 64, tile);
    } else {
        const int tt = bid - 6144;
        transpose_64x64(r_proj, rprojT, 256, 256, (tt >> 2) * 64, (tt & 3) * 64,
                        tile);
    }
}

// --------------------------------------------------------------------------
// gemm_diff: block = 128n x 256d (full D), BK=32, K=2304 (72 k-tiles:
// 64 of W|preT + 8 of cur(f32->bf16 in reg)|rprojT). 16x16x32 MFMA.
// 4 waves 2x2 (wm: 64n halves, wn: 128d halves), 4x8 MFMAs per wave.
// A operand: direct global loads (no LDS). B operand: GLL16 -> LDS.
// Epilogue: sum_d diff^2 -> Ssq[b,n] = sqrt(.), plain store.
// --------------------------------------------------------------------------
__global__ __launch_bounds__(256, 2) void gemm_diff(
    const unsigned short* __restrict__ Wneg,    // (2048,2048) bf16 neg+masked
    const float* __restrict__ cur,              // (32,2048,256) f32
    const unsigned short* __restrict__ preT,    // (32,256,2048) bf16
    const unsigned short* __restrict__ rprojT,  // (256,256) bf16
    float* __restrict__ Ssq)                    // (32,2048)
{
    const int n0 = blockIdx.x * 128;
    const int b  = blockIdx.y;

    __shared__ unsigned short Bl[256 * 32];   // 16 KB
    __shared__ float ssq[128];

    const int tid  = threadIdx.x;
    const int w    = tid >> 6;
    const int lane = tid & 63;
    const int l16  = lane & 15;
    const int quad = lane >> 4;
    const int wm   = w >> 1, wn = w & 1;

    if (tid < 128) ssq[tid] = 0.f;

    f32x4 acc[4][8] = {};

    const float*          curB = cur  + (size_t)b * 2048 * 256;
    const unsigned short* preB = preT + (size_t)b * 256 * 2048;

    const int srow  = lane >> 2;        // 0..15
    const int sbyte = (lane & 3) * 16;  // bytes within a 64B row-chunk

    // Per-lane A row base: rows wm*64 + mi*16 + l16, k-chunk quad*8
    const unsigned short* aW = Wneg + (size_t)(n0 + wm * 64 + l16) * 2048 + quad * 8;
    const float*          aC = curB + (size_t)(n0 + wm * 64 + l16) * 256 + quad * 8;

    for (int kt = 0; kt < 72; ++kt) {
        // ---- A fragments: direct global -> VGPR (no barrier dependency) ----
        bf16x8 af[4];
        if (kt < 64) {
            const int k0 = kt * 32;
#pragma unroll
            for (int mi = 0; mi < 4; ++mi)
                af[mi] = *(const bf16x8*)(aW + (size_t)mi * 16 * 2048 + k0);
        } else {
            const int kk = kt * 32 - 2048;
#pragma unroll
            for (int mi = 0; mi < 4; ++mi) {
                const float* p = aC + (size_t)mi * 16 * 256 + kk;
                float4 v0 = *(const float4*)(p);
                float4 v1 = *(const float4*)(p + 4);
                bf16x8 a;
                a[0] = (short)f2bf(v0.x); a[1] = (short)f2bf(v0.y);
                a[2] = (short)f2bf(v0.z); a[3] = (short)f2bf(v0.w);
                a[4] = (short)f2bf(v1.x); a[5] = (short)f2bf(v1.y);
                a[6] = (short)f2bf(v1.z); a[7] = (short)f2bf(v1.w);
                af[mi] = a;
            }
        }

        // ---- B tile: global_load_lds staging ----
        __syncthreads();  // previous B tile fully consumed
        if (kt < 64) {
            const unsigned short* bb = preB + kt * 32;
#pragma unroll
            for (int j = 0; j < 4; ++j) {
                const int row = w * 64 + j * 16 + srow;
                GLL16((const char*)(bb + (size_t)row * 2048) + sbyte,
                      (char*)Bl + w * 4096 + j * 1024);
            }
        } else {
            const unsigned short* bb = rprojT + (kt * 32 - 2048);
#pragma unroll
            for (int j = 0; j < 4; ++j) {
                const int row = w * 64 + j * 16 + srow;
                GLL16((const char*)(bb + (size_t)row * 256) + sbyte,
                      (char*)Bl + w * 4096 + j * 1024);
            }
        }
        __syncthreads();  // staging visible

        bf16x8 bfr[8];
#pragma unroll
        for (int ni = 0; ni < 8; ++ni)
            bfr[ni] = *(const bf16x8*)(Bl + (wn * 128 + ni * 16 + l16) * 32 + quad * 8);
#pragma unroll
        for (int mi = 0; mi < 4; ++mi)
#pragma unroll
            for (int ni = 0; ni < 8; ++ni)
                acc[mi][ni] = __builtin_amdgcn_mfma_f32_16x16x32_bf16(
                    af[mi], bfr[ni], acc[mi][ni], 0, 0, 0);
    }
    __syncthreads();

    // C/D layout: col = lane&15 (d), row = quad*4 + reg (n) [verified m89/m91]
#pragma unroll
    for (int mi = 0; mi < 4; ++mi)
#pragma unroll
        for (int r = 0; r < 4; ++r) {
            float s = 0.f;
#pragma unroll
            for (int ni = 0; ni < 8; ++ni) {
                float v = acc[mi][ni][r];
                s += v * v;
            }
            s += __shfl_xor(s, 1);
            s += __shfl_xor(s, 2);
            s += __shfl_xor(s, 4);
            s += __shfl_xor(s, 8);
            if (l16 == 0)   // 2-way (wn) accumulate in LDS
                atomicAdd(&ssq[wm * 64 + mi * 16 + quad * 4 + r], s);
        }
    __syncthreads();
    if (tid < 128)
        Ssq[(size_t)b * 2048 + n0 + tid] = sqrtf(ssq[tid]);
}

// --------------------------------------------------------------------------
// finalize: loss[b] = 0.2 * sum_n Ssq[b,n] + sum_n crow[n]
// --------------------------------------------------------------------------
__global__ void finalize(const float* __restrict__ Ssq,
                         const float* __restrict__ crow,
                         float* __restrict__ out) {
    const int b = blockIdx.x;
    float s1 = 0.f, s2 = 0.f;
    for (int i = threadIdx.x; i < 2048; i += 256) {
        s1 += Ssq[(size_t)b * 2048 + i];
        s2 += crow[i];
    }
#pragma unroll
    for (int off = 32; off; off >>= 1) {
        s1 += __shfl_down(s1, off);
        s2 += __shfl_down(s2, off);
    }
    __shared__ float sm1[4], sm2[4];
    int wv = threadIdx.x >> 6, ln = threadIdx.x & 63;
    if (ln == 0) { sm1[wv] = s1; sm2[wv] = s2; }
    __syncthreads();
    if (threadIdx.x == 0)
        out[b] = 0.2f * (sm1[0] + sm1[1] + sm1[2] + sm1[3])
               + (sm2[0] + sm2[1] + sm2[2] + sm2[3]);
}

// --------------------------------------------------------------------------
extern "C" void kernel_launch(void* const* d_in, const int* in_sizes, int n_in,
                              void* d_out, int out_size, void* d_ws, size_t ws_size,
                              hipStream_t stream) {
    const float* cur    = (const float*)d_in[0];  // (32,2048,256)
    const float* pre    = (const float*)d_in[1];  // (32,2048,256)
    const float* r_proj = (const float*)d_in[2];  // (256,256)
    const float* inc    = (const float*)d_in[3];  // (2048,2048)
    float* out = (float*)d_out;                   // [0..31]=loss, [32..]=incidence

    char* ws = (char*)d_ws;
    unsigned short* Wneg   = (unsigned short*)(ws + 0);          //  8 MB
    unsigned short* preT   = (unsigned short*)(ws + 8388608);    // 32 MB
    unsigned short* rprojT = (unsigned short*)(ws + 41943040);   // 128 KB
    float*          Sbuf   = (float*)(ws + 42074112);            // 256 KB
    float*          crow   = (float*)(ws + 42336256);            // 8 KB

    prep_all<<<6160, 256, 0, stream>>>(inc, out + 32, Wneg, crow,
                                       pre, preT, r_proj, rprojT);
    gemm_diff<<<dim3(16, 32), 256, 0, stream>>>(Wneg, cur, preT, rprojT, Sbuf);
    finalize<<<32, 256, 0, stream>>>(Sbuf, crow, out);
}